// Round 11
// baseline (157.552 us; speedup 1.0000x reference)
//
#include <hip/hip_runtime.h>

typedef float f32x4 __attribute__((ext_vector_type(4)));
typedef int   i32x4 __attribute__((ext_vector_type(4)));
typedef short b16x8 __attribute__((ext_vector_type(8)));

__device__ __forceinline__ short f2b(float v) {   // f32 -> bf16 (RNE)
  union { float f; unsigned u; } x; x.f = v;
  unsigned r = x.u + 0x7FFFu + ((x.u >> 16) & 1u);
  return (short)(r >> 16);
}
__device__ __forceinline__ float b2f(short s) {   // bf16 -> f32
  union { unsigned u; float f; } x; x.u = ((unsigned)(unsigned short)s) << 16;
  return x.f;
}

#define WT_ELEMS   (9 * 128 * 128)     // wT[k][o][c]
#define WOFF_ELEMS (9 * 32 * 128)      // wOffT[k][o(pad32)][c]
#define XT_BYTES   (8u * 4096u * 128u * 2u)   // x_t[b][y*64+x][c] bf16 = 8 MB

// ---- prep: reorder weights to tap-major bf16 ----
__global__ __launch_bounds__(256) void prep_w(
    const float* __restrict__ w_off, const float* __restrict__ w_dcn,
    short* __restrict__ wT, short* __restrict__ wOffT)
{
  int t = blockIdx.x * 256 + threadIdx.x;
  int stride = gridDim.x * 256;
  for (int i = t; i < WT_ELEMS; i += stride) {
    int k = i >> 14, r = i & 16383, o = r >> 7, c = r & 127;
    wT[i] = f2b(w_dcn[o * 1152 + c * 9 + k]);
  }
  for (int i = t; i < WOFF_ELEMS; i += stride) {
    int k = i >> 12, r = i & 4095, o = r >> 7, c = r & 127;
    wOffT[i] = (o < 18) ? f2b(w_off[o * 1152 + c * 9 + k]) : (short)0;
  }
}

// ---- transpose x[b][c][y][w] f32 -> x_t[b][y][w][c] bf16 ----
__global__ __launch_bounds__(256) void transp(
    const float* __restrict__ xg, short* __restrict__ xt)
{
  __shared__ float tile[32][65];
  const int bid = blockIdx.x;
  const int b = bid >> 6, y = bid & 63;
  const int t = threadIdx.x;
  const float* src = xg + ((size_t)b << 19) + y * 64;
  short*       dst = xt + ((size_t)b << 19) + (size_t)y * 8192;

  for (int ct = 0; ct < 4; ++ct) {
    __syncthreads();
    int c_l = t >> 3, w0 = (t & 7) * 8;
    const float* p = src + (size_t)(ct * 32 + c_l) * 4096 + w0;
    f32x4 a0 = *(const f32x4*)p;
    f32x4 a1 = *(const f32x4*)(p + 4);
    #pragma unroll
    for (int i = 0; i < 4; ++i) { tile[c_l][w0 + i] = a0[i]; tile[c_l][w0 + 4 + i] = a1[i]; }
    __syncthreads();
    int w = t >> 2, j0 = (t & 3) * 8;
    b16x8 pk;
    #pragma unroll
    for (int j = 0; j < 8; ++j) pk[j] = f2b(tile[j0 + j][w]);
    *(b16x8*)(dst + w * 128 + ct * 32 + j0) = pk;
  }
}

// ---- fused deformable conv: phase-2 is wave-private & barrier-free ----
// block = 32 px (b, ho, wo0..wo0+31), 256 threads = 4 waves.
// wave wv: px-group (wv&1)*16..+15, o-half (wv>>1)*64..+63.
// Each lane gathers+lerps exactly its own MFMA B-fragment:
//   lane l <- px = pxg*16 + (l&15), channels kk*32 + (l>>4)*8 .. +8.
__global__ __launch_bounds__(256, 4) void dcn_mfma(
    const short* __restrict__ xt, const float* __restrict__ b_off,
    const short* __restrict__ wT, const short* __restrict__ wOffT,
    float* __restrict__ out)
{
  // arena: phase1 window W[102 pos][128c] bf16 swizzled (26112 B);
  //        after phase1: idxA/wtA tables at +16384 (9216 B, inside arena)
  __shared__ __align__(16) char  arena[26112];
  __shared__ __align__(16) float offT[32 * 32];

  char*  sW   = arena;
  i32x4* idxA = (i32x4*)(arena + 16384);
  f32x4* wtA  = (f32x4*)(arena + 16384 + 4608);

  const int tid  = threadIdx.x;
  const int lane = tid & 63;
  const int wv_  = tid >> 6;
  const int bid  = blockIdx.x;
  const int swz  = (bid & 7) * 128 + (bid >> 3);   // batch -> one XCD (L2 locality)
  const int b    = swz >> 7;
  const int ho   = (swz >> 1) & 63;
  const int wo0  = (swz & 1) * 32;

  const int l15  = lane & 15;
  const int l4   = lane >> 4;

  const short* xb = xt + ((size_t)b << 19);

  // ---- stage phase-1 window: 3 rows x 34 cols x 128 ch (rolled) ----
  #pragma unroll 1
  for (int i = 0; i < 7; ++i) {
    int s = tid + i * 256;
    if (s < 1632) {                       // 102 positions * 16 chunks
      int p = s >> 4, cc = s & 15;
      int py = p / 34, pxw = p - py * 34;
      int y = ho - 1 + py, xw = wo0 + pxw - 1;
      bool v = ((unsigned)y < 64u) && ((unsigned)xw < 64u);
      b16x8 q = {0,0,0,0,0,0,0,0};
      if (v) q = *(const b16x8*)(xb + ((size_t)(y * 64 + xw) << 7) + cc * 8);
      *(b16x8*)(sW + p * 256 + ((cc * 16) ^ ((p & 7) << 4))) = q;
    }
  }
  __syncthreads();

  // ---- phase 1: offset conv (rolled tap loop) ----
  f32x4 accP = {0.f, 0.f, 0.f, 0.f};
  const int fo = wv_ >> 1, fp = wv_ & 1;
  {
    const int bpx = fp * 16 + l15;
    #pragma unroll 1
    for (int k = 0; k < 9; ++k) {
      int ky = k / 3, kx = k - ky * 3;
      int p  = ky * 34 + bpx + kx;
      const short* wk = wOffT + k * 4096;
      #pragma unroll
      for (int kk = 0; kk < 4; ++kk) {
        int cf = kk * 32 + l4 * 8;
        b16x8 a  = *(const b16x8*)(wk + (fo * 16 + l15) * 128 + cf);
        b16x8 bb = *(const b16x8*)(sW + p * 256 + ((cf * 2) ^ ((p & 7) << 4)));
        accP = __builtin_amdgcn_mfma_f32_16x16x32_bf16(a, bb, accP, 0, 0, 0);
      }
    }
  }
  {
    int px = fp * 16 + l15;
    int ob = fo * 16 + l4 * 4;
    #pragma unroll
    for (int r = 0; r < 4; ++r)
      offT[(ob + r) * 32 + px] = accP[r];
  }
  __syncthreads();   // all phase-1 window reads done; offT visible

  // ---- bilinear tables for ALL 9 taps (rolled) ----
  #pragma unroll 1
  for (int i = 0; i < 2; ++i) {
    int item = tid + i * 256;
    if (item < 288) {
      int k = item >> 5, px = item & 31;
      int ky = k / 3, kx = k - ky * 3;
      float dy = offT[(2 * k) * 32 + px]     + b_off[2 * k];
      float dx = offT[(2 * k + 1) * 32 + px] + b_off[2 * k + 1];
      float yy = (float)(ho - 1 + ky) + dy;
      float xx = (float)(wo0 + px - 1 + kx) + dx;
      float y0f = floorf(yy), x0f = floorf(xx);
      float wy = yy - y0f, wx = xx - x0f;
      int y0 = (int)y0f, x0 = (int)x0f;
      int y1 = y0 + 1, x1 = x0 + 1;
      int cy0 = min(max(y0, 0), 63), cx0 = min(max(x0, 0), 63);
      int cy1 = min(max(y1, 0), 63), cx1 = min(max(x1, 0), 63);
      float vy0 = ((unsigned)y0 < 64u) ? 1.f : 0.f;
      float vy1 = ((unsigned)y1 < 64u) ? 1.f : 0.f;
      float vx0 = ((unsigned)x0 < 64u) ? 1.f : 0.f;
      float vx1 = ((unsigned)x1 < 64u) ? 1.f : 0.f;
      i32x4 iv; iv[0] = cy0*64+cx0; iv[1] = cy0*64+cx1; iv[2] = cy1*64+cx0; iv[3] = cy1*64+cx1;
      f32x4 wvv;
      wvv[0] = (1.f - wy) * (1.f - wx) * vy0 * vx0;
      wvv[1] = (1.f - wy) * wx         * vy0 * vx1;
      wvv[2] = wy         * (1.f - wx) * vy1 * vx0;
      wvv[3] = wy         * wx         * vy1 * vx1;
      idxA[item] = iv; wtA[item] = wvv;
    }
  }
  __syncthreads();   // tables ready; NO MORE BARRIERS from here on

  // ---- phase 2: wave-private sample + contract, zero barriers ----
  const int pxg   = wv_ & 1;          // px-group: 16 px
  const int ohalf = wv_ >> 1;         // o-half:   64 o
  const int mypx  = pxg * 16 + l15;   // this lane's pixel
  const int coff  = l4 * 8;           // this lane's channel sub-offset

  f32x4 acc0 = {0,0,0,0}, acc1 = {0,0,0,0}, acc2 = {0,0,0,0}, acc3 = {0,0,0,0};

  #pragma unroll
  for (int k = 0; k < 9; ++k) {
    i32x4 iv  = idxA[k * 32 + mypx];
    f32x4 wvv = wtA[k * 32 + mypx];
    const short* r0 = xb + (size_t)iv[0] * 128 + coff;
    const short* r1 = xb + (size_t)iv[1] * 128 + coff;
    const short* r2 = xb + (size_t)iv[2] * 128 + coff;
    const short* r3 = xb + (size_t)iv[3] * 128 + coff;
    const short* wk = wT + k * 16384 + ohalf * 64 * 128 + coff;

    #pragma unroll
    for (int kk = 0; kk < 4; ++kk) {
      int cc = kk * 32;
      b16x8 q0 = *(const b16x8*)(r0 + cc);
      b16x8 q1 = *(const b16x8*)(r1 + cc);
      b16x8 q2 = *(const b16x8*)(r2 + cc);
      b16x8 q3 = *(const b16x8*)(r3 + cc);
      b16x8 sfrag;
      #pragma unroll
      for (int j = 0; j < 8; ++j) {
        float v = wvv[0] * b2f(q0[j]) + wvv[1] * b2f(q1[j]) +
                  wvv[2] * b2f(q2[j]) + wvv[3] * b2f(q3[j]);
        sfrag[j] = f2b(v);
      }
      b16x8 a0 = *(const b16x8*)(wk + (0 * 16 + l15) * 128 + cc);
      b16x8 a1 = *(const b16x8*)(wk + (1 * 16 + l15) * 128 + cc);
      b16x8 a2 = *(const b16x8*)(wk + (2 * 16 + l15) * 128 + cc);
      b16x8 a3 = *(const b16x8*)(wk + (3 * 16 + l15) * 128 + cc);
      acc0 = __builtin_amdgcn_mfma_f32_16x16x32_bf16(a0, sfrag, acc0, 0, 0, 0);
      acc1 = __builtin_amdgcn_mfma_f32_16x16x32_bf16(a1, sfrag, acc1, 0, 0, 0);
      acc2 = __builtin_amdgcn_mfma_f32_16x16x32_bf16(a2, sfrag, acc2, 0, 0, 0);
      acc3 = __builtin_amdgcn_mfma_f32_16x16x32_bf16(a3, sfrag, acc3, 0, 0, 0);
    }
  }

  // ---- epilogue: wave writes o-half x its 16 px ----
  {
    size_t base = ((size_t)b * 128) * 4096 + (size_t)ho * 64 + wo0 + pxg * 16;
    int o0 = ohalf * 64 + l4 * 4;
    #pragma unroll
    for (int r = 0; r < 4; ++r) {
      out[base + (size_t)(o0 + r) * 4096 + l15]      = acc0[r];
      out[base + (size_t)(o0 + 16 + r) * 4096 + l15] = acc1[r];
      out[base + (size_t)(o0 + 32 + r) * 4096 + l15] = acc2[r];
      out[base + (size_t)(o0 + 48 + r) * 4096 + l15] = acc3[r];
    }
  }
}

extern "C" void kernel_launch(void* const* d_in, const int* in_sizes, int n_in,
                              void* d_out, int out_size, void* d_ws, size_t ws_size,
                              hipStream_t stream) {
  const float* x     = (const float*)d_in[0];
  const float* w_off = (const float*)d_in[1];
  const float* b_off = (const float*)d_in[2];
  const float* w_dcn = (const float*)d_in[3];
  float* out = (float*)d_out;

  short* xt    = (short*)d_ws;                                    // 8,388,608 B
  short* wT    = (short*)((char*)d_ws + XT_BYTES);                // 294,912 B
  short* wOffT = (short*)((char*)d_ws + XT_BYTES + WT_ELEMS * 2); // 73,728 B

  hipLaunchKernelGGL(prep_w,   dim3(64),   dim3(256), 0, stream, w_off, w_dcn, wT, wOffT);
  hipLaunchKernelGGL(transp,   dim3(512),  dim3(256), 0, stream, x, xt);
  hipLaunchKernelGGL(dcn_mfma, dim3(1024), dim3(256), 0, stream, xt, b_off, wT, wOffT, out);
}

// Round 12
// 48.654 us; speedup vs baseline: 3.2382x; 3.2382x over previous
//
#include <hip/hip_runtime.h>

typedef float f32x4 __attribute__((ext_vector_type(4)));
typedef int   i32x4 __attribute__((ext_vector_type(4)));
typedef short b16x8 __attribute__((ext_vector_type(8)));

__device__ __forceinline__ short f2b(float v) {   // f32 -> bf16 (RNE)
  union { float f; unsigned u; } x; x.f = v;
  unsigned r = x.u + 0x7FFFu + ((x.u >> 16) & 1u);
  return (short)(r >> 16);
}
__device__ __forceinline__ float b2f(short s) {   // bf16 -> f32
  union { unsigned u; float f; } x; x.u = ((unsigned)(unsigned short)s) << 16;
  return x.f;
}

#define WT_ELEMS   (9 * 128 * 128)     // fragment-linear: [k][og:8][kk:4][lane:64][8]
#define WOFF_ELEMS (9 * 32 * 128)      // fragment-linear: [k][fo:2][kk:4][lane:64][8]
#define XT_BYTES   (8u * 4096u * 128u * 2u)   // x_t[b][y*64+x][c] bf16 = 8 MB

// ---- prep: weights -> tap-major, FRAGMENT-LINEAR bf16 ----
// A wave's A-fragment load becomes  base + lane*16B  (coalesced 1KB burst).
// Fragment mapping (mfma_f32_16x16x32_bf16 A): o = og*16 + (lane&15),
// c = kk*32 + (lane>>4)*8 + j.
__global__ __launch_bounds__(256) void prep_w(
    const float* __restrict__ w_off, const float* __restrict__ w_dcn,
    short* __restrict__ wT, short* __restrict__ wOffT)
{
  int t = blockIdx.x * 256 + threadIdx.x;
  int stride = gridDim.x * 256;
  for (int i = t; i < WT_ELEMS; i += stride) {
    int j    = i & 7;
    int lane = (i >> 3) & 63;
    int kk   = (i >> 9) & 3;
    int og   = (i >> 11) & 7;
    int k    = i >> 14;
    int o = og * 16 + (lane & 15);
    int c = kk * 32 + (lane >> 4) * 8 + j;
    wT[i] = f2b(w_dcn[o * 1152 + c * 9 + k]);
  }
  for (int i = t; i < WOFF_ELEMS; i += stride) {
    int j    = i & 7;
    int lane = (i >> 3) & 63;
    int kk   = (i >> 9) & 3;
    int fo   = (i >> 11) & 1;
    int k    = i >> 12;
    int o = fo * 16 + (lane & 15);
    int c = kk * 32 + (lane >> 4) * 8 + j;
    wOffT[i] = (o < 18) ? f2b(w_off[o * 1152 + c * 9 + k]) : (short)0;
  }
}

// ---- transpose x[b][c][y][w] f32 -> x_t[b][y][w][c] bf16 ----
__global__ __launch_bounds__(256) void transp(
    const float* __restrict__ xg, short* __restrict__ xt)
{
  __shared__ float tile[32][65];
  const int bid = blockIdx.x;
  const int b = bid >> 6, y = bid & 63;
  const int t = threadIdx.x;
  const float* src = xg + ((size_t)b << 19) + y * 64;
  short*       dst = xt + ((size_t)b << 19) + (size_t)y * 8192;

  for (int ct = 0; ct < 4; ++ct) {
    __syncthreads();
    int c_l = t >> 3, w0 = (t & 7) * 8;
    const float* p = src + (size_t)(ct * 32 + c_l) * 4096 + w0;
    f32x4 a0 = *(const f32x4*)p;
    f32x4 a1 = *(const f32x4*)(p + 4);
    #pragma unroll
    for (int i = 0; i < 4; ++i) { tile[c_l][w0 + i] = a0[i]; tile[c_l][w0 + 4 + i] = a1[i]; }
    __syncthreads();
    int w = t >> 2, j0 = (t & 3) * 8;
    b16x8 pk;
    #pragma unroll
    for (int j = 0; j < 8; ++j) pk[j] = f2b(tile[j0 + j][w]);
    *(b16x8*)(dst + w * 128 + ct * 32 + j0) = pk;
  }
}

// ---------- helpers ----------
__device__ __forceinline__ void gather8(const short* xb, const i32x4* idxA,
                                        int k, int px_s, int cg, b16x8 (&g)[8]) {
  i32x4 iv = idxA[k * 32 + px_s];
  const short* r0 = xb + (size_t)iv[0] * 128;
  const short* r1 = xb + (size_t)iv[1] * 128;
  const short* r2 = xb + (size_t)iv[2] * 128;
  const short* r3 = xb + (size_t)iv[3] * 128;
  int c0 = cg * 8, c1 = 64 + cg * 8;
  g[0] = *(const b16x8*)(r0 + c0);  g[1] = *(const b16x8*)(r0 + c1);
  g[2] = *(const b16x8*)(r1 + c0);  g[3] = *(const b16x8*)(r1 + c1);
  g[4] = *(const b16x8*)(r2 + c0);  g[5] = *(const b16x8*)(r2 + c1);
  g[6] = *(const b16x8*)(r3 + c0);  g[7] = *(const b16x8*)(r3 + c1);
}

__device__ __forceinline__ void lerp_write(char* sbuf, const f32x4* wtA,
                                           int k, int px_s, int cg, const b16x8 (&g)[8]) {
  f32x4 wv = wtA[k * 32 + px_s];
  #pragma unroll
  for (int it = 0; it < 2; ++it) {
    b16x8 pk;
    #pragma unroll
    for (int j = 0; j < 8; ++j) {
      float v = wv[0] * b2f(g[0 + it][j]) + wv[1] * b2f(g[2 + it][j]) +
                wv[2] * b2f(g[4 + it][j]) + wv[3] * b2f(g[6 + it][j]);
      pk[j] = f2b(v);
    }
    int c0 = it * 64 + cg * 8;
    *(b16x8*)(sbuf + px_s * 256 + ((c0 * 2) ^ ((px_s & 7) << 4))) = pk;
  }
}

// weight loads are now COALESCED: base + lane*16B (fragment-linear layout)
__device__ __forceinline__ void mfma_tap(const char* sbuf, const short* wkfrag,
                                         int lane, int l15, int l4,
                                         f32x4& a00, f32x4& a01, f32x4& a10, f32x4& a11) {
  #pragma unroll
  for (int kk = 0; kk < 4; ++kk) {
    int cf = kk * 32 + l4 * 8;
    b16x8 w0 = *(const b16x8*)(wkfrag + ((0 * 4 + kk) << 9) + lane * 8);
    b16x8 w1 = *(const b16x8*)(wkfrag + ((1 * 4 + kk) << 9) + lane * 8);
    b16x8 b0 = *(const b16x8*)(sbuf + l15 * 256        + ((cf * 2) ^ ((l15 & 7) << 4)));
    b16x8 b1 = *(const b16x8*)(sbuf + (16 + l15) * 256 + ((cf * 2) ^ ((l15 & 7) << 4)));
    a00 = __builtin_amdgcn_mfma_f32_16x16x32_bf16(w0, b0, a00, 0, 0, 0);
    a01 = __builtin_amdgcn_mfma_f32_16x16x32_bf16(w0, b1, a01, 0, 0, 0);
    a10 = __builtin_amdgcn_mfma_f32_16x16x32_bf16(w1, b0, a10, 0, 0, 0);
    a11 = __builtin_amdgcn_mfma_f32_16x16x32_bf16(w1, b1, a11, 0, 0, 0);
  }
}

// ---- fused deformable conv (r10 structure; weights fragment-linear) ----
// block = 32 px (b, ho, wo0..wo0+31), 256 threads = 4 waves.
__global__ __launch_bounds__(256, 4) void dcn_mfma(
    const short* __restrict__ xt, const float* __restrict__ b_off,
    const short* __restrict__ wT, const short* __restrict__ wOffT,
    float* __restrict__ out)
{
  // arena: phase1 = window W[102 pos][128c] bf16 swizzled (26112 B)
  //        phase2 = sS0(8192) | sS1(8192) | idxA(4608) | wtA(4608)
  __shared__ __align__(16) char  arena[26112];
  __shared__ __align__(16) float offT[32 * 32];

  char*  sW   = arena;
  char*  sS0  = arena;
  char*  sS1  = arena + 8192;
  i32x4* idxA = (i32x4*)(arena + 16384);
  f32x4* wtA  = (f32x4*)(arena + 16384 + 4608);

  const int tid  = threadIdx.x;
  const int lane = tid & 63;
  const int wv_  = tid >> 6;
  const int bid  = blockIdx.x;
  const int swz  = (bid & 7) * 128 + (bid >> 3);   // batch -> one XCD (L2 locality)
  const int b    = swz >> 7;
  const int ho   = (swz >> 1) & 63;
  const int wo0  = (swz & 1) * 32;

  const int px_s = tid >> 3;       // 0..31
  const int cg   = tid & 7;        // 0..7
  const int l15  = lane & 15;
  const int l4   = lane >> 4;

  const short* xb = xt + ((size_t)b << 19);

  // ---- stage phase-1 window: 3 rows x 34 cols x 128 ch (rolled) ----
  #pragma unroll 1
  for (int i = 0; i < 7; ++i) {
    int s = tid + i * 256;
    if (s < 1632) {
      int p = s >> 4, cc = s & 15;
      int py = p / 34, pxw = p - py * 34;
      int y = ho - 1 + py, xw = wo0 + pxw - 1;
      bool v = ((unsigned)y < 64u) && ((unsigned)xw < 64u);
      b16x8 q = {0,0,0,0,0,0,0,0};
      if (v) q = *(const b16x8*)(xb + ((size_t)(y * 64 + xw) << 7) + cc * 8);
      *(b16x8*)(sW + p * 256 + ((cc * 16) ^ ((p & 7) << 4))) = q;
    }
  }
  __syncthreads();

  // ---- phase 1: offset conv (rolled; coalesced weight frags) ----
  f32x4 accP = {0.f, 0.f, 0.f, 0.f};
  const int fo = wv_ >> 1, fp = wv_ & 1;
  {
    const int bpx = fp * 16 + l15;
    #pragma unroll 1
    for (int k = 0; k < 9; ++k) {
      int ky = k / 3, kx = k - ky * 3;
      int p  = ky * 34 + bpx + kx;
      const short* wkf = wOffT + (((k * 2 + fo) * 4) << 9);
      #pragma unroll
      for (int kk = 0; kk < 4; ++kk) {
        int cf = kk * 32 + l4 * 8;
        b16x8 a  = *(const b16x8*)(wkf + (kk << 9) + lane * 8);
        b16x8 bb = *(const b16x8*)(sW + p * 256 + ((cf * 2) ^ ((p & 7) << 4)));
        accP = __builtin_amdgcn_mfma_f32_16x16x32_bf16(a, bb, accP, 0, 0, 0);
      }
    }
  }
  {
    int px = fp * 16 + l15;
    int ob = fo * 16 + l4 * 4;
    #pragma unroll
    for (int r = 0; r < 4; ++r)
      offT[(ob + r) * 32 + px] = accP[r];
  }
  __syncthreads();   // all phase-1 window reads done; offT visible

  // ---- bilinear tables for ALL 9 taps (rolled) ----
  #pragma unroll 1
  for (int i = 0; i < 2; ++i) {
    int item = tid + i * 256;
    if (item < 288) {
      int k = item >> 5, px = item & 31;
      int ky = k / 3, kx = k - ky * 3;
      float dy = offT[(2 * k) * 32 + px]     + b_off[2 * k];
      float dx = offT[(2 * k + 1) * 32 + px] + b_off[2 * k + 1];
      float yy = (float)(ho - 1 + ky) + dy;
      float xx = (float)(wo0 + px - 1 + kx) + dx;
      float y0f = floorf(yy), x0f = floorf(xx);
      float wy = yy - y0f, wx = xx - x0f;
      int y0 = (int)y0f, x0 = (int)x0f;
      int y1 = y0 + 1, x1 = x0 + 1;
      int cy0 = min(max(y0, 0), 63), cx0 = min(max(x0, 0), 63);
      int cy1 = min(max(y1, 0), 63), cx1 = min(max(x1, 0), 63);
      float vy0 = ((unsigned)y0 < 64u) ? 1.f : 0.f;
      float vy1 = ((unsigned)y1 < 64u) ? 1.f : 0.f;
      float vx0 = ((unsigned)x0 < 64u) ? 1.f : 0.f;
      float vx1 = ((unsigned)x1 < 64u) ? 1.f : 0.f;
      i32x4 iv; iv[0] = cy0*64+cx0; iv[1] = cy0*64+cx1; iv[2] = cy1*64+cx0; iv[3] = cy1*64+cx1;
      f32x4 wvv;
      wvv[0] = (1.f - wy) * (1.f - wx) * vy0 * vx0;
      wvv[1] = (1.f - wy) * wx         * vy0 * vx1;
      wvv[2] = wy         * (1.f - wx) * vy1 * vx0;
      wvv[3] = wy         * wx         * vy1 * vx1;
      idxA[item] = iv; wtA[item] = wvv;
    }
  }
  __syncthreads();   // tables ready

  // ---- phase 2: sample + contract, rolled, r10-proven sync ----
  f32x4 acc00 = {0,0,0,0}, acc01 = {0,0,0,0}, acc10 = {0,0,0,0}, acc11 = {0,0,0,0};
  // wave's weight fragments: og pair (wv_*2, wv_*2+1), fragment-linear
  b16x8 g[8];

  #pragma unroll 1
  for (int k = 0; k < 9; ++k) {
    char* sb = (k & 1) ? sS1 : sS0;
    gather8(xb, idxA, k, px_s, cg, g);
    lerp_write(sb, wtA, k, px_s, cg, g);
    __syncthreads();
    const short* wkfrag = wT + (((k * 8 + wv_ * 2) * 4) << 9);
    mfma_tap(sb, wkfrag, lane, l15, l4, acc00, acc01, acc10, acc11);
  }

  // ---- epilogue ----
  {
    size_t base = ((size_t)b * 128) * 4096 + (size_t)ho * 64 + wo0;
    int o0 = wv_ * 32 + l4 * 4;
    #pragma unroll
    for (int r = 0; r < 4; ++r) {
      out[base + (size_t)(o0 + r) * 4096 + l15]           = acc00[r];
      out[base + (size_t)(o0 + r) * 4096 + 16 + l15]      = acc01[r];
      out[base + (size_t)(o0 + 16 + r) * 4096 + l15]      = acc10[r];
      out[base + (size_t)(o0 + 16 + r) * 4096 + 16 + l15] = acc11[r];
    }
  }
}

extern "C" void kernel_launch(void* const* d_in, const int* in_sizes, int n_in,
                              void* d_out, int out_size, void* d_ws, size_t ws_size,
                              hipStream_t stream) {
  const float* x     = (const float*)d_in[0];
  const float* w_off = (const float*)d_in[1];
  const float* b_off = (const float*)d_in[2];
  const float* w_dcn = (const float*)d_in[3];
  float* out = (float*)d_out;

  short* xt    = (short*)d_ws;                                    // 8,388,608 B
  short* wT    = (short*)((char*)d_ws + XT_BYTES);                // 294,912 B
  short* wOffT = (short*)((char*)d_ws + XT_BYTES + WT_ELEMS * 2); // 73,728 B

  hipLaunchKernelGGL(prep_w,   dim3(64),   dim3(256), 0, stream, w_off, w_dcn, wT, wOffT);
  hipLaunchKernelGGL(transp,   dim3(512),  dim3(256), 0, stream, x, xt);
  hipLaunchKernelGGL(dcn_mfma, dim3(1024), dim3(256), 0, stream, xt, b_off, wT, wOffT, out);
}